// Round 5
// baseline (433.725 us; speedup 1.0000x reference)
//
#include <hip/hip_runtime.h>

#define BB 128
#define TT 1024
#define VV 192
#define NTHREADS 256
#define NWAVES 4
#define NCHUNK 8
#define WARM 16
#define LN2 0.69314718055994530942f
// per-batch ws: F[192], Bv[192], then 16 slots of 3: contrib, gold, seqlen.
// 448 floats/batch = 229376 B total == R1-proven workspace budget.
#define WS_STRIDE 448

typedef int   intx8   __attribute__((ext_vector_type(8)));
typedef float floatx2 __attribute__((ext_vector_type(2)));
typedef float floatx4 __attribute__((ext_vector_type(4)));

__device__ __forceinline__ float bf8_to_f32(unsigned char h) {
    floatx2 v = __builtin_amdgcn_cvt_pk_f32_bf8((int)(unsigned int)h, false);
    return v.x;
}
__device__ __forceinline__ unsigned char f32_to_bf8(float f) {
    int pk = __builtin_amdgcn_cvt_pk_bf8_f32(f, f, 0, false);
    return (unsigned char)(pk & 0xff);
}
__device__ __forceinline__ unsigned char f32_to_fp8(float f) {
    int pk = __builtin_amdgcn_cvt_pk_fp8_f32(f, f, 0, false);
    return (unsigned char)(pk & 0xff);
}

// LDS-only barrier: does NOT drain vmcnt (global loads stay in flight)
#define LBAR() __asm__ volatile("s_waitcnt lgkmcnt(0)\n\ts_barrier" ::: "memory")

// Chunked bidirectional scan. DIR=0 fwd alpha steps t=1..512; DIR=1 bwd delta
// steps u=1..510 + final plain matvec -> Bv. Chunk c covers real steps
// [64c+1, 64c+64] (bwd c7: [449,510]); chunks c>0 warm-start 16 steps earlier
// from a uniform state — the renormalized step map is scale-invariant (depends
// only on ratios) and contracts ratios by ~0.39/step (Birkhoff), so 16 steps
// converge to the monolithic trajectory below bf8 ULP. Scale telescoping:
//   T_dir = sum_c [ carry2_c + (c<7 ? P_c : 0) - (c>0 ? R_c : 0) ]
// with P/R = log2(state byte0 at chunk end/start) — P_c and R_{c+1} cancel to
// quantization noise; chunk 0 starts from the true init so the chain is exact.
template<int DIR>
__device__ __forceinline__ void crf_body(const float* __restrict__ emissions,
                                         const int* __restrict__ tags,
                                         const int* __restrict__ mask,
                                         const float* __restrict__ trans,
                                         const float* __restrict__ start_trans,
                                         const float* __restrict__ end_trans,
                                         float* __restrict__ ws,
                                         int chunk)
{
    const int b = blockIdx.x;
    const int tid = threadIdx.x;
    const int lane = tid & 63;
    const int wid = tid >> 6;        // 0..3
    const int quad = lane >> 4;      // 0..3
    const int col = lane & 15;       // 0..15

    __shared__ __align__(16) unsigned char qpad[2][256];
    __shared__ unsigned int smaskp[33];   // packed mask bits, word 32 = 0 pad

    const float* em_b = emissions + (size_t)b * TT * VV;
    const int* mask_b = mask + b * TT;
    float* wsb = ws + (size_t)b * WS_STRIDE;

    // quads 0..2 own one column; quad 3 duplicates quad 0 (rows of the matvec
    // result are identical since the A-operand replicates V across rows)
    const int nl = wid * 48 + (quad < 3 ? quad : 0) * 16 + col;

    const int first = (chunk == 0) ? 1 : (64 * chunk - WARM + 1);  // first dostep
    const bool haswarm = (chunk > 0);
    const bool tail14 = (DIR == 1 && chunk == 7);
    const int nwin = (chunk == 0) ? 4 : (tail14 ? 4 : 5);

    #define ROW_OF(g) (DIR ? (TT - 1 - (g)) : (g))

    // ---- E fragments, e4m3, MX 16x16x128 B-operand: 2 K-tiles x 3 N-tiles ----
    intx8 ef[6];
    #pragma unroll
    for (int kt = 0; kt < 2; ++kt) {
        #pragma unroll
        for (int h = 0; h < 3; ++h) {
            const int n = wid * 48 + h * 16 + col;
            intx8 v;
            #pragma unroll
            for (int w = 0; w < 8; ++w) {
                unsigned int word = 0;
                #pragma unroll
                for (int by = 0; by < 4; ++by) {
                    int k = kt * 128 + quad * 32 + w * 4 + by;
                    float x = (k < VV) ? __expf(trans[DIR ? (k + n * VV) : (k * VV + n)]) : 0.f;
                    word |= (unsigned int)f32_to_fp8(x) << (8 * by);
                }
                v[w] = (int)word;
            }
            ef[kt * 3 + h] = v;
        }
    }

    // ---- zero both Q buffers (pad bytes 192..255 must stay 0 forever) ----
    for (int i = tid; i < 512; i += NTHREADS) ((unsigned char*)qpad)[i] = 0;

    // ---- build packed mask bits ----
    if (tid < 33) {
        if (tid == 32) smaskp[32] = 0u;
        else {
            unsigned int m = 0;
            #pragma unroll 4
            for (int j = 0; j < 32; ++j) m |= (mask_b[tid * 32 + j] ? 1u : 0u) << j;
            smaskp[tid] = m;
        }
    }

    // ---- raw emission registers (exp applied lazily); dostep j uses row ROW_OF(first+j)
    float em0[8], em1[8];
    #pragma unroll
    for (int r = 0; r < 8; ++r) em0[r] = em_b[(size_t)ROW_OF(first + r) * VV + nl];
    #pragma unroll
    for (int r = 0; r < 8; ++r) em1[r] = em_b[(size_t)ROW_OF(first + 8 + r) * VV + nl];
    // peprev = pe of row preceding the first dostep (bwd masked path only)
    float peprev = __expf(em_b[(size_t)ROW_OF(first - 1) * VV + nl]);

    // ---- init state ----
    __syncthreads();   // zero-fill + smaskp visible before init write
    if (tid < VV) {
        if (chunk == 0) {
            float a0 = DIR ? (end_trans[tid] + em_b[(size_t)(TT - 1) * VV + tid])
                           : (start_trans[tid] + em_b[tid]);
            qpad[0][tid] = f32_to_bf8(fminf(__expf(a0), 28672.f));
        } else {
            qpad[0][tid] = f32_to_bf8(1.0f);   // uniform warm init (scale irrelevant)
        }
    }
    float carry2 = 0.f, Rv = 0.f;
    int cur = 0;
    __syncthreads();

    // per-window scalar mask fetch: window covers global steps gw..gw+15
    unsigned long long mk64 = 0; int shbase = 0;
    auto fetchwin = [&](int gw) {
        int base = DIR ? (1024 - gw - 15) : gw;
        unsigned lo = (unsigned)__builtin_amdgcn_readfirstlane((int)smaskp[base >> 5]);
        unsigned hi = (unsigned)__builtin_amdgcn_readfirstlane((int)smaskp[(base >> 5) + 1]);
        mk64 = (((unsigned long long)hi) << 32) | (unsigned long long)lo;
        shbase = base & 31;
    };
    auto getmk = [&](int i) -> int {
        int sh = DIR ? (shbase + 15 - i) : (shbase + i);
        return (int)((mk64 >> sh) & 1ull);
    };

    // one CRF step: consumes qpad[cur]; emraw = raw em[row][nl]; mk = mask bit
    auto dostep = [&](float emraw, int mk) {
        unsigned char* qc = qpad[cur];
        const intx8* qv = (const intx8*)qc;
        intx8 A0 = qv[quad];        // state bytes [quad*32, quad*32+32)
        intx8 A1 = qv[quad + 4];    // state bytes [128+quad*32, ...)
        unsigned char prevb = 0;
        if (!mk) prevb = qc[nl];    // uniform branch; skipped when mask=1

        floatx4 aA[3], aB[3];
        #pragma unroll
        for (int h = 0; h < 3; ++h) { aA[h] = (floatx4){0.f,0.f,0.f,0.f};
                                      aB[h] = (floatx4){0.f,0.f,0.f,0.f}; }
        #pragma unroll
        for (int h = 0; h < 3; ++h)
            aA[h] = __builtin_amdgcn_mfma_scale_f32_16x16x128_f8f6f4(
                        A0, ef[h], aA[h], 1, 0, 0, 0x7f7f7f7f, 0, 0x7f7f7f7f);
        #pragma unroll
        for (int h = 0; h < 3; ++h)
            aB[h] = __builtin_amdgcn_mfma_scale_f32_16x16x128_f8f6f4(
                        A1, ef[3 + h], aB[h], 1, 0, 0, 0x7f7f7f7f, 0, 0x7f7f7f7f);

        int q0i = __builtin_amdgcn_readfirstlane(A0[0]);   // state byte 0
        float q0 = bf8_to_f32((unsigned char)(q0i & 0xff));
        float r = __builtin_amdgcn_rcpf(q0);
        carry2 += mk ? __log2f(q0) : 0.f;
        float pe = __expf(emraw);
        float sc = pe * r;

        float s0 = aA[0][0] + aB[0][0];
        float s1 = aA[1][0] + aB[1][0];
        float s2 = aA[2][0] + aB[2][0];
        float v = (quad == 1) ? s1 : ((quad == 2) ? s2 : s0);  // quad3 dups quad0
        float qn = fminf(v * sc, 28672.f);
        unsigned char nb;
        if (mk) {
            nb = f32_to_bf8(qn);
        } else {
            nb = DIR ? f32_to_bf8(fminf(bf8_to_f32(prevb) * pe *
                                        __builtin_amdgcn_rcpf(peprev), 28672.f))
                     : prevb;
        }
        qpad[cur ^ 1][nl] = nb;     // unconditional; quad3 writes identical dup
        LBAR();
        cur ^= 1;
        if (DIR) peprev = pe;
    };

    // ---- window loop ----
    int jw = 0;
    for (int w = 0; w < nwin; ++w, jw += 16) {
        fetchwin(first + jw);
        dostep(em0[0], getmk(0));
        dostep(em0[1], getmk(1));
        dostep(em0[2], getmk(2));
        dostep(em0[3], getmk(3));
        dostep(em0[4], getmk(4));
        dostep(em0[5], getmk(5));
        dostep(em0[6], getmk(6));
        dostep(em0[7], getmk(7));
        {   // refill em0 <- j = jw+16..jw+23 (junk on last window; in-bounds)
            #pragma unroll
            for (int r = 0; r < 8; ++r) {
                int g = first + jw + 16 + r;
                em0[r] = em_b[(size_t)ROW_OF(g) * VV + nl];
            }
        }
        dostep(em1[0], getmk(8));
        dostep(em1[1], getmk(9));
        dostep(em1[2], getmk(10));
        dostep(em1[3], getmk(11));
        dostep(em1[4], getmk(12));
        dostep(em1[5], getmk(13));
        dostep(em1[6], getmk(14));
        dostep(em1[7], getmk(15));
        {   // refill em1 <- j = jw+24..jw+31
            #pragma unroll
            for (int r = 0; r < 8; ++r) {
                int g = first + jw + 24 + r;
                em1[r] = em_b[(size_t)ROW_OF(g) * VV + nl];
            }
        }
        if (haswarm && w == 0) {
            // warm-up done: capture start-state scale, reset carry
            Rv = __log2f(bf8_to_f32(qpad[cur][0]));
            carry2 = 0.f;
        }
    }
    if (tail14) {   // bwd chunk 7: 14 more steps (u=497..510)
        fetchwin(first + jw);
        dostep(em0[0], getmk(0));
        dostep(em0[1], getmk(1));
        dostep(em0[2], getmk(2));
        dostep(em0[3], getmk(3));
        dostep(em0[4], getmk(4));
        dostep(em0[5], getmk(5));
        dostep(em0[6], getmk(6));
        dostep(em0[7], getmk(7));
        dostep(em1[0], getmk(8));
        dostep(em1[1], getmk(9));
        dostep(em1[2], getmk(10));
        dostep(em1[3], getmk(11));
        dostep(em1[4], getmk(12));
        dostep(em1[5], getmk(13));
    }

    // ---- chunk exports ----
    float Pv = __log2f(bf8_to_f32(qpad[cur][0]));   // end-state scale

    if (DIR == 0 && chunk == 7) {
        // F = final fwd state (alpha_512 normalized), as f32
        if (tid < VV) wsb[tid] = bf8_to_f32(qpad[cur][tid]);
    }
    if (DIR == 1 && chunk == 7) {
        // final plain matvec (no pe, no renorm): Bv from D_513, mask m_513
        unsigned char* qc = qpad[cur];
        const intx8* qv = (const intx8*)qc;
        intx8 A0 = qv[quad];
        intx8 A1 = qv[quad + 4];
        int mk = (int)((smaskp[513 >> 5] >> (513 & 31)) & 1u);
        floatx4 aA[3], aB[3];
        #pragma unroll
        for (int h = 0; h < 3; ++h) { aA[h] = (floatx4){0.f,0.f,0.f,0.f};
                                      aB[h] = (floatx4){0.f,0.f,0.f,0.f}; }
        #pragma unroll
        for (int h = 0; h < 3; ++h)
            aA[h] = __builtin_amdgcn_mfma_scale_f32_16x16x128_f8f6f4(
                        A0, ef[h], aA[h], 1, 0, 0, 0x7f7f7f7f, 0, 0x7f7f7f7f);
        #pragma unroll
        for (int h = 0; h < 3; ++h)
            aB[h] = __builtin_amdgcn_mfma_scale_f32_16x16x128_f8f6f4(
                        A1, ef[3 + h], aB[h], 1, 0, 0, 0x7f7f7f7f, 0, 0x7f7f7f7f);
        if (quad < 3) {
            float s0 = aA[0][0] + aB[0][0];
            float s1 = aA[1][0] + aB[1][0];
            float s2 = aA[2][0] + aB[2][0];
            float v = (quad == 1) ? s1 : ((quad == 2) ? s2 : s0);
            if (!mk) v = bf8_to_f32(qc[nl]) * __builtin_amdgcn_rcpf(peprev);
            wsb[192 + nl] = v;
        }
    }

    // ---- gold partials: fwd chunk c: t in [64c+1, 64c+64]; bwd: [513+64c, +gcnt) ----
    const int glo = DIR ? (513 + 64 * chunk) : (64 * chunk + 1);
    const int gcnt = tail14 ? 63 : 64;
    float gp = 0.f;
    if (tid < gcnt) {
        int t = glo + tid;
        int mk = (int)((smaskp[t >> 5] >> (t & 31)) & 1u);
        int tg  = tags[b * TT + t];
        int tgp = tags[b * TT + t - 1];
        gp = mk ? (em_b[(size_t)t * VV + tg] + trans[tgp * VV + tg]) : 0.f;
    }
    #pragma unroll
    for (int off = 1; off < 64; off <<= 1) gp += __shfl_xor(gp, off);

    if (tid == 0) {
        if (DIR == 0 && chunk == 0) {
            int tg0 = tags[b * TT];
            gp += start_trans[tg0] + em_b[tg0];
        }
        // seqlen over [slo, slo+64): two aligned mask words
        int slo = DIR ? (512 + 64 * chunk) : (64 * chunk);
        float sl = (float)(__popc(smaskp[slo >> 5]) + __popc(smaskp[(slo >> 5) + 1]));
        // fold P/R into a single per-chunk contribution (saves ws space)
        float contrib = carry2;
        if (chunk < NCHUNK - 1) contrib += Pv;
        if (chunk > 0)          contrib -= Rv;
        float* slot = wsb + 384 + (DIR * NCHUNK + chunk) * 3;
        slot[0] = contrib;
        slot[1] = gp;
        slot[2] = sl;
    }
    #undef ROW_OF
}

__launch_bounds__(NTHREADS, 1)
__global__ void crf_chunk_kernel(const float* __restrict__ emissions,
                                 const int* __restrict__ tags,
                                 const int* __restrict__ mask,
                                 const float* __restrict__ trans,
                                 const float* __restrict__ start_trans,
                                 const float* __restrict__ end_trans,
                                 float* __restrict__ ws)
{
    const int dir = blockIdx.y & 1;
    const int chunk = blockIdx.y >> 1;
    if (dir == 0)
        crf_body<0>(emissions, tags, mask, trans, start_trans, end_trans, ws, chunk);
    else
        crf_body<1>(emissions, tags, mask, trans, start_trans, end_trans, ws, chunk);
}

// combine: T = sum contrib; logden = LN2*T + log(dot(F,Bv));
// loss = (logden - gold)/seq_len
__global__ void crf_combine(const float* __restrict__ ws,
                            const int* __restrict__ tags,
                            const float* __restrict__ end_trans,
                            float* __restrict__ out)
{
    const int b = blockIdx.x;
    const int lane = threadIdx.x;   // 64 threads
    const float* wsb = ws + (size_t)b * WS_STRIDE;
    float s = 0.f;
    #pragma unroll
    for (int i = lane; i < VV; i += 64) s += wsb[i] * wsb[192 + i];
    #pragma unroll
    for (int off = 1; off < 64; off <<= 1) s += __shfl_xor(s, off);
    if (lane == 0) {
        float T = 0.f, gold = 0.f, seq = 0.f;
        for (int k = 0; k < 2 * NCHUNK; ++k) {
            const float* slot = wsb + 384 + k * 3;
            T    += slot[0];
            gold += slot[1];
            seq  += slot[2];
        }
        float logden = LN2 * T + __logf(s + 1e-8f);
        int seqs = (int)(seq + 0.5f);
        int last_idx = seqs - 1; if (last_idx < 0) last_idx = 0;
        gold += end_trans[tags[b * TT + last_idx]];
        float seqf = fmaxf((float)seqs, 1.0f);
        out[b] = (logden - gold) / seqf;
    }
}

extern "C" void kernel_launch(void* const* d_in, const int* in_sizes, int n_in,
                              void* d_out, int out_size, void* d_ws, size_t ws_size,
                              hipStream_t stream) {
    const float* emissions   = (const float*)d_in[0];
    const int*   tags        = (const int*)d_in[1];
    const int*   mask        = (const int*)d_in[2];
    const float* trans       = (const float*)d_in[3];
    const float* start_trans = (const float*)d_in[4];
    const float* end_trans   = (const float*)d_in[5];
    float* out = (float*)d_out;
    float* ws  = (float*)d_ws;   // 128*448*4 = 229376 B (== R1-proven budget)

    crf_chunk_kernel<<<dim3(BB, 2 * NCHUNK), NTHREADS, 0, stream>>>(
        emissions, tags, mask, trans, start_trans, end_trans, ws);
    crf_combine<<<BB, 64, 0, stream>>>(ws, tags, end_trans, out);
}

// Round 7
// 409.945 us; speedup vs baseline: 1.0580x; 1.0580x over previous
//
#include <hip/hip_runtime.h>

#define BB 128
#define TT 1024
#define VV 192
#define NTHREADS 256
#define LN2 0.69314718055994530942f
// per-batch ws: F[192], Bv[192], per-dir 8 slots: contrib[4], gold, seq
#define WS_STRIDE 448

typedef int   intx8   __attribute__((ext_vector_type(8)));
typedef float floatx2 __attribute__((ext_vector_type(2)));
typedef float floatx4 __attribute__((ext_vector_type(4)));

__device__ __forceinline__ float bf8_to_f32(unsigned char h) {
    floatx2 v = __builtin_amdgcn_cvt_pk_f32_bf8((int)(unsigned int)h, false);
    return v.x;
}
__device__ __forceinline__ unsigned char f32_to_bf8(float f) {
    int pk = __builtin_amdgcn_cvt_pk_bf8_f32(f, f, 0, false);
    return (unsigned char)(pk & 0xff);
}
__device__ __forceinline__ unsigned char f32_to_fp8(float f) {
    int pk = __builtin_amdgcn_cvt_pk_fp8_f32(f, f, 0, false);
    return (unsigned char)(pk & 0xff);
}

// LDS-only barrier: does NOT drain vmcnt (global loads stay in flight)
#define LBAR() __asm__ volatile("s_waitcnt lgkmcnt(0)\n\ts_barrier" ::: "memory")

// 4-chain ILP: one 256-thread block per (batch, dir) interleaves the 4 chunk
// recurrences (R5-validated warm-up chunking; junctions 128/256/384). Each
// round = 1 step of each chain: 8 ds_read_b128 -> 24 independent MFMAs ->
// 4 epilogues -> ONE barrier. Chain geometry (per dir):
//  c0: first=1,  no warm, P at L=128 (16 harmless trailing steps to L=144)
//  c1: first=113, R at L=16, P at L=144 (=step 256)
//  c2: first=241, R at L=16, P at L=144 (=step 384)
//  c3 fwd: first=369, R at L=16, real to L=144 (=t=512), exports F
//  c3 bwd: first=367, R at L=18, real to L=144 (=u=510), final matvec -> Bv
// contrib_c = carry_c + (c<3 ? P_c : 0) - (c>0 ? R_c : 0); T = sum contribs.
template<int DIR>
__device__ __forceinline__ void crf_body(const float* __restrict__ emissions,
                                         const int* __restrict__ tags,
                                         const int* __restrict__ mask,
                                         const float* __restrict__ trans,
                                         const float* __restrict__ start_trans,
                                         const float* __restrict__ end_trans,
                                         float* __restrict__ ws)
{
    const int b = blockIdx.x;
    const int tid = threadIdx.x;
    const int lane = tid & 63;
    const int wid = tid >> 6;        // 0..3
    const int quad = lane >> 4;      // 0..3
    const int col = lane & 15;       // 0..15

    __shared__ __align__(16) unsigned char qpad[4][2][256];
    __shared__ unsigned int smaskp[33];   // packed mask bits, word 32 = 0 pad
    __shared__ float wgs[4], wsls[4];

    const float* em_b = emissions + (size_t)b * TT * VV;
    const int* mask_b = mask + b * TT;
    float* wsb = ws + (size_t)b * WS_STRIDE;

    // quads 0..2 own one column; quad 3 duplicates quad 0
    const int nl = wid * 48 + (quad < 3 ? quad : 0) * 16 + col;

    const int firstc[4] = {1, 113, 241, DIR ? 367 : 369};
    const int capRc[4]  = {0, 16, 16, DIR ? 18 : 16};
    const int capPc[4]  = {128, 144, 144, 0};

    #define ROW_OF(x) (DIR ? (TT - 1 - (x)) : (x))

    // ---- E fragments, e4m3, MX 16x16x128 B-operand (shared by all chains) ----
    intx8 ef[6];
    #pragma unroll
    for (int kt = 0; kt < 2; ++kt) {
        #pragma unroll
        for (int h = 0; h < 3; ++h) {
            const int n = wid * 48 + h * 16 + col;
            intx8 v;
            #pragma unroll
            for (int w = 0; w < 8; ++w) {
                unsigned int word = 0;
                #pragma unroll
                for (int by = 0; by < 4; ++by) {
                    int k = kt * 128 + quad * 32 + w * 4 + by;
                    float x = (k < VV) ? __expf(trans[DIR ? (k + n * VV) : (k * VV + n)]) : 0.f;
                    word |= (unsigned int)f32_to_fp8(x) << (8 * by);
                }
                v[w] = (int)word;
            }
            ef[kt * 3 + h] = v;
        }
    }

    // ---- zero all Q buffers (pad bytes 192..255 must stay 0 forever) ----
    for (int i = tid; i < 4 * 512; i += NTHREADS) ((unsigned char*)qpad)[i] = 0;

    // ---- build packed mask bits ----
    if (tid < 33) {
        if (tid == 32) smaskp[32] = 0u;
        else {
            unsigned int m = 0;
            #pragma unroll 4
            for (int j = 0; j < 32; ++j) m |= (mask_b[tid * 32 + j] ? 1u : 0u) << j;
            smaskp[tid] = m;
        }
    }

    // ---- raw emission registers per chain; step local L uses row ROW_OF(first+L-1)
    float em0[4][8], em1[4][8];
    #pragma unroll
    for (int c = 0; c < 4; ++c) {
        #pragma unroll
        for (int r = 0; r < 8; ++r) em0[c][r] = em_b[(size_t)ROW_OF(firstc[c] + r) * VV + nl];
        #pragma unroll
        for (int r = 0; r < 8; ++r) em1[c][r] = em_b[(size_t)ROW_OF(firstc[c] + 8 + r) * VV + nl];
    }
    float pep[4] = {0.f, 0.f, 0.f, 0.f};
    if (DIR) {
        #pragma unroll
        for (int c = 0; c < 4; ++c)
            pep[c] = __expf(em_b[(size_t)ROW_OF(firstc[c] - 1) * VV + nl]);
    }

    // ---- init states ----
    __syncthreads();   // zero-fill + smaskp visible
    if (tid < VV) {
        float a0 = DIR ? (end_trans[tid] + em_b[(size_t)(TT - 1) * VV + tid])
                       : (start_trans[tid] + em_b[tid]);
        qpad[0][0][tid] = f32_to_bf8(fminf(__expf(a0), 28672.f));
        unsigned char one = f32_to_bf8(1.0f);
        qpad[1][0][tid] = one;   // uniform warm init (scale irrelevant)
        qpad[2][0][tid] = one;
        qpad[3][0][tid] = one;
    }
    float carry[4] = {0.f,0.f,0.f,0.f}, Rv[4] = {0.f,0.f,0.f,0.f};
    float Pv[4] = {0.f,0.f,0.f,0.f}, csv[4] = {0.f,0.f,0.f,0.f};
    int cur = 0;
    __syncthreads();

    unsigned long long mk64[4];
    int shb[4];

#define GETMK(c, I) ((int)((mk64[c] >> (DIR ? (shb[c] + 15 - (I)) : (shb[c] + (I)))) & 1ull))

// one round = one step of each chain; I is a literal 0..15
#define ROUND(I)                                                               \
    {                                                                          \
        intx8 a0_[4], a1_[4];                                                  \
        _Pragma("unroll")                                                      \
        for (int c = 0; c < 4; ++c) {                                          \
            const intx8* qv = (const intx8*)qpad[c][cur];                      \
            a0_[c] = qv[quad];                                                 \
            a1_[c] = qv[quad + 4];                                             \
        }                                                                      \
        floatx4 aA_[4][3], aB_[4][3];                                          \
        _Pragma("unroll")                                                      \
        for (int c = 0; c < 4; ++c) {                                          \
            _Pragma("unroll")                                                  \
            for (int h = 0; h < 3; ++h) {                                      \
                floatx4 z = (floatx4){0.f, 0.f, 0.f, 0.f};                     \
                aA_[c][h] = __builtin_amdgcn_mfma_scale_f32_16x16x128_f8f6f4(  \
                    a0_[c], ef[h], z, 1, 0, 0, 0x7f7f7f7f, 0, 0x7f7f7f7f);     \
                aB_[c][h] = __builtin_amdgcn_mfma_scale_f32_16x16x128_f8f6f4(  \
                    a1_[c], ef[3 + h], z, 1, 0, 0, 0x7f7f7f7f, 0, 0x7f7f7f7f); \
            }                                                                  \
        }                                                                      \
        _Pragma("unroll")                                                      \
        for (int c = 0; c < 4; ++c) {                                          \
            int mk = GETMK(c, I);                                              \
            unsigned char prevb = 0;                                           \
            if (!mk) prevb = qpad[c][cur][nl];                                 \
            int q0i = __builtin_amdgcn_readfirstlane(a0_[c][0]);               \
            float q0 = bf8_to_f32((unsigned char)(q0i & 0xff));                \
            float rr = __builtin_amdgcn_rcpf(q0);                              \
            carry[c] += mk ? __log2f(q0) : 0.f;                                \
            float emraw = ((I) < 8) ? em0[c][(I) & 7] : em1[c][(I) & 7];       \
            float pe = __expf(emraw);                                          \
            float sc = pe * rr;                                                \
            float s0 = aA_[c][0][0] + aB_[c][0][0];                            \
            float s1 = aA_[c][1][0] + aB_[c][1][0];                            \
            float s2 = aA_[c][2][0] + aB_[c][2][0];                            \
            float vv = (quad == 1) ? s1 : ((quad == 2) ? s2 : s0);             \
            float qn = fminf(vv * sc, 28672.f);                                \
            unsigned char nb;                                                  \
            if (mk) nb = f32_to_bf8(qn);                                       \
            else nb = DIR ? f32_to_bf8(fminf(bf8_to_f32(prevb) * pe *          \
                                 __builtin_amdgcn_rcpf(pep[c]), 28672.f))      \
                          : prevb;                                             \
            qpad[c][cur ^ 1][nl] = nb;                                         \
            if (DIR) pep[c] = pe;                                              \
        }                                                                      \
        LBAR();                                                                \
        cur ^= 1;                                                              \
        {                                                                      \
            int L = lb + (I) + 1;                                              \
            _Pragma("unroll")                                                  \
            for (int c = 0; c < 4; ++c) {                                      \
                if (L == capRc[c]) {                                           \
                    Rv[c] = __log2f(bf8_to_f32(qpad[c][cur][0]));              \
                    carry[c] = 0.f;                                            \
                }                                                              \
                if (L == capPc[c]) {                                           \
                    Pv[c] = __log2f(bf8_to_f32(qpad[c][cur][0]));              \
                    csv[c] = carry[c];                                         \
                }                                                              \
            }                                                                  \
        }                                                                      \
    }

    // ---- main loop: 9 windows x 16 rounds = 144 locksteps ----
    for (int w = 0; w < 9; ++w) {
        const int lb = 16 * w;
        #pragma unroll
        for (int c = 0; c < 4; ++c) {
            int gw = firstc[c] + lb;
            int base = DIR ? (1024 - gw - 15) : gw;
            unsigned lo = (unsigned)__builtin_amdgcn_readfirstlane((int)smaskp[base >> 5]);
            unsigned hi = (unsigned)__builtin_amdgcn_readfirstlane((int)smaskp[(base >> 5) + 1]);
            mk64[c] = (((unsigned long long)hi) << 32) | (unsigned long long)lo;
            shb[c] = base & 31;
        }
        ROUND(0) ROUND(1) ROUND(2) ROUND(3)
        ROUND(4) ROUND(5) ROUND(6) ROUND(7)
        {   // refill em0 (junk on last window; all addresses in-bounds)
            #pragma unroll
            for (int c = 0; c < 4; ++c) {
                #pragma unroll
                for (int r = 0; r < 8; ++r)
                    em0[c][r] = em_b[(size_t)ROW_OF(firstc[c] + lb + 16 + r) * VV + nl];
            }
        }
        ROUND(8) ROUND(9) ROUND(10) ROUND(11)
        ROUND(12) ROUND(13) ROUND(14) ROUND(15)
        {   // refill em1
            #pragma unroll
            for (int c = 0; c < 4; ++c) {
                #pragma unroll
                for (int r = 0; r < 8; ++r)
                    em1[c][r] = em_b[(size_t)ROW_OF(firstc[c] + lb + 24 + r) * VV + nl];
            }
        }
    }
#undef ROUND
#undef GETMK

    csv[3] = carry[3];   // c3 exports carry at end (no P)

    // ---- exports ----
    if (DIR == 0) {
        // F = state after t=512 (alpha_512 normalized)
        if (tid < VV) wsb[tid] = bf8_to_f32(qpad[3][cur][tid]);
    } else {
        // final plain matvec (no pe, no renorm): Bv from D_513, mask m_513
        const intx8* qv = (const intx8*)qpad[3][cur];
        intx8 A0 = qv[quad];
        intx8 A1 = qv[quad + 4];
        int mkf = (int)((smaskp[513 >> 5] >> (513 & 31)) & 1u);
        floatx4 aA[3], aB[3];
        #pragma unroll
        for (int h = 0; h < 3; ++h) {
            floatx4 z = (floatx4){0.f, 0.f, 0.f, 0.f};
            aA[h] = __builtin_amdgcn_mfma_scale_f32_16x16x128_f8f6f4(
                        A0, ef[h], z, 1, 0, 0, 0x7f7f7f7f, 0, 0x7f7f7f7f);
            aB[h] = __builtin_amdgcn_mfma_scale_f32_16x16x128_f8f6f4(
                        A1, ef[3 + h], z, 1, 0, 0, 0x7f7f7f7f, 0, 0x7f7f7f7f);
        }
        if (quad < 3) {
            float s0 = aA[0][0] + aB[0][0];
            float s1 = aA[1][0] + aB[1][0];
            float s2 = aA[2][0] + aB[2][0];
            float vv = (quad == 1) ? s1 : ((quad == 2) ? s2 : s0);
            if (!mkf) vv = bf8_to_f32(qpad[3][cur][nl]) * __builtin_amdgcn_rcpf(pep[3]);
            wsb[192 + nl] = vv;
        }
    }
    if (tid == 0) {
        #pragma unroll
        for (int c = 0; c < 4; ++c) {
            float contrib = csv[c] + ((c < 3) ? Pv[c] : 0.f) - ((c > 0) ? Rv[c] : 0.f);
            wsb[384 + DIR * 8 + c] = contrib;
        }
    }

    // ---- gold score + seq_len partials (this dir's t-range) ----
    float gp = 0.f, sl = 0.f;
    for (int t = tid; t < TT; t += NTHREADS) {
        int mk = (int)((smaskp[t >> 5] >> (t & 31)) & 1u);
        bool inS = DIR ? (t >= 512) : (t < 512);
        if (inS) sl += (float)mk;
        bool inG = DIR ? (t >= 513) : (t >= 1 && t <= 512);
        if (inG) {
            int tg  = tags[b * TT + t];
            int tgp = tags[b * TT + t - 1];
            float term = em_b[(size_t)t * VV + tg] + trans[tgp * VV + tg];
            gp += mk ? term : 0.f;
        }
    }
    #pragma unroll
    for (int off = 1; off < 64; off <<= 1) {
        gp += __shfl_xor(gp, off);
        sl += __shfl_xor(sl, off);
    }
    if (lane == 0) { wgs[wid] = gp; wsls[wid] = sl; }
    __syncthreads();
    if (tid == 0) {
        float g = 0.f, s = 0.f;
        for (int w = 0; w < 4; ++w) { g += wgs[w]; s += wsls[w]; }
        if (DIR == 0) {
            int tg0 = tags[b * TT];
            g += start_trans[tg0] + em_b[tg0];
        }
        wsb[384 + DIR * 8 + 4] = g;
        wsb[384 + DIR * 8 + 5] = s;
    }
    #undef ROW_OF
}

__launch_bounds__(NTHREADS, 1)
__global__ void crf_ilp_kernel(const float* __restrict__ emissions,
                               const int* __restrict__ tags,
                               const int* __restrict__ mask,
                               const float* __restrict__ trans,
                               const float* __restrict__ start_trans,
                               const float* __restrict__ end_trans,
                               float* __restrict__ ws)
{
    if (blockIdx.y == 0)
        crf_body<0>(emissions, tags, mask, trans, start_trans, end_trans, ws);
    else
        crf_body<1>(emissions, tags, mask, trans, start_trans, end_trans, ws);
}

// combine: T = sum contribs; logden = LN2*T + log(dot(F,Bv));
// loss = (logden - gold)/seq_len
__global__ void crf_combine(const float* __restrict__ ws,
                            const int* __restrict__ tags,
                            const float* __restrict__ end_trans,
                            float* __restrict__ out)
{
    const int b = blockIdx.x;
    const int lane = threadIdx.x;   // 64 threads
    const float* wsb = ws + (size_t)b * WS_STRIDE;
    float s = 0.f;
    #pragma unroll
    for (int i = lane; i < VV; i += 64) s += wsb[i] * wsb[192 + i];
    #pragma unroll
    for (int off = 1; off < 64; off <<= 1) s += __shfl_xor(s, off);
    if (lane == 0) {
        float T = 0.f, gold = 0.f, seq = 0.f;
        for (int d = 0; d < 2; ++d) {
            const float* slot = wsb + 384 + d * 8;
            T    += slot[0] + slot[1] + slot[2] + slot[3];
            gold += slot[4];
            seq  += slot[5];
        }
        float logden = LN2 * T + __logf(s + 1e-8f);
        int seqs = (int)(seq + 0.5f);
        int last_idx = seqs - 1; if (last_idx < 0) last_idx = 0;
        gold += end_trans[tags[b * TT + last_idx]];
        float seqf = fmaxf((float)seqs, 1.0f);
        out[b] = (logden - gold) / seqf;
    }
}

extern "C" void kernel_launch(void* const* d_in, const int* in_sizes, int n_in,
                              void* d_out, int out_size, void* d_ws, size_t ws_size,
                              hipStream_t stream) {
    const float* emissions   = (const float*)d_in[0];
    const int*   tags        = (const int*)d_in[1];
    const int*   mask        = (const int*)d_in[2];
    const float* trans       = (const float*)d_in[3];
    const float* start_trans = (const float*)d_in[4];
    const float* end_trans   = (const float*)d_in[5];
    float* out = (float*)d_out;
    float* ws  = (float*)d_ws;   // 128*448*4 = 229376 B (proven budget)

    crf_ilp_kernel<<<dim3(BB, 2), NTHREADS, 0, stream>>>(
        emissions, tags, mask, trans, start_trans, end_trans, ws);
    crf_combine<<<BB, 64, 0, stream>>>(ws, tags, end_trans, out);
}

// Round 8
// 252.472 us; speedup vs baseline: 1.7179x; 1.6237x over previous
//
#include <hip/hip_runtime.h>

#define BB 128
#define TT 1024
#define VV 192
#define NTHREADS 256
#define LN2 0.69314718055994530942f
// per-batch ws: F[192], Bv[192], per-dir 8 slots: contrib[4], gold, seq
#define WS_STRIDE 448

typedef int   intx8   __attribute__((ext_vector_type(8)));
typedef float floatx2 __attribute__((ext_vector_type(2)));
typedef float floatx4 __attribute__((ext_vector_type(4)));

__device__ __forceinline__ float bf8_to_f32(unsigned char h) {
    floatx2 v = __builtin_amdgcn_cvt_pk_f32_bf8((int)(unsigned int)h, false);
    return v.x;
}
__device__ __forceinline__ unsigned char f32_to_bf8(float f) {
    int pk = __builtin_amdgcn_cvt_pk_bf8_f32(f, f, 0, false);
    return (unsigned char)(pk & 0xff);
}
__device__ __forceinline__ unsigned char f32_to_fp8(float f) {
    int pk = __builtin_amdgcn_cvt_pk_fp8_f32(f, f, 0, false);
    return (unsigned char)(pk & 0xff);
}

// LDS-only barrier: does NOT drain vmcnt (global loads stay in flight)
#define LBAR() __asm__ volatile("s_waitcnt lgkmcnt(0)\n\ts_barrier" ::: "memory")

// 4-chain ILP (R7 structure, proven correct) + forced register budget
// (amdgpu_waves_per_eu(1,1)) + sched_group_barrier pinning so the 4 chains
// actually overlap: per round {12 DS reads} -> {24 MFMAs} -> epilogues.
// Chain geometry per dir (R5/R7-validated warm-up chunking):
//  c0: first=1,  no warm, P at L=128
//  c1: first=113, R at L=16, P at L=144 (=step 256)
//  c2: first=241, R at L=16, P at L=144 (=step 384)
//  c3 fwd: first=369, R at L=16, real to L=144 (=t=512), exports F
//  c3 bwd: first=367, R at L=18, real to L=144 (=u=510), final matvec -> Bv
// contrib_c = carry_c + (c<3 ? P_c : 0) - (c>0 ? R_c : 0); T = sum contribs.
template<int DIR>
__device__ __forceinline__ void crf_body(const float* __restrict__ emissions,
                                         const int* __restrict__ tags,
                                         const int* __restrict__ mask,
                                         const float* __restrict__ trans,
                                         const float* __restrict__ start_trans,
                                         const float* __restrict__ end_trans,
                                         float* __restrict__ ws)
{
    const int b = blockIdx.x;
    const int tid = threadIdx.x;
    const int lane = tid & 63;
    const int wid = tid >> 6;        // 0..3
    const int quad = lane >> 4;      // 0..3
    const int col = lane & 15;       // 0..15

    __shared__ __align__(16) unsigned char qpad[4][2][256];
    __shared__ unsigned int smaskp[33];   // packed mask bits, word 32 = 0 pad
    __shared__ float wgs[4], wsls[4];

    const float* em_b = emissions + (size_t)b * TT * VV;
    const int* mask_b = mask + b * TT;
    float* wsb = ws + (size_t)b * WS_STRIDE;

    // quads 0..2 own one column; quad 3 duplicates quad 0
    const int nl = wid * 48 + (quad < 3 ? quad : 0) * 16 + col;

    const int firstc[4] = {1, 113, 241, DIR ? 367 : 369};
    const int capRc[4]  = {0, 16, 16, DIR ? 18 : 16};
    const int capPc[4]  = {128, 144, 144, 0};

    #define ROW_OF(x) (DIR ? (TT - 1 - (x)) : (x))

    // ---- E fragments, e4m3, MX 16x16x128 B-operand (shared by all chains) ----
    intx8 ef[6];
    #pragma unroll
    for (int kt = 0; kt < 2; ++kt) {
        #pragma unroll
        for (int h = 0; h < 3; ++h) {
            const int n = wid * 48 + h * 16 + col;
            intx8 v;
            #pragma unroll
            for (int w = 0; w < 8; ++w) {
                unsigned int word = 0;
                #pragma unroll
                for (int by = 0; by < 4; ++by) {
                    int k = kt * 128 + quad * 32 + w * 4 + by;
                    float x = (k < VV) ? __expf(trans[DIR ? (k + n * VV) : (k * VV + n)]) : 0.f;
                    word |= (unsigned int)f32_to_fp8(x) << (8 * by);
                }
                v[w] = (int)word;
            }
            ef[kt * 3 + h] = v;
        }
    }

    // ---- zero all Q buffers (pad bytes 192..255 must stay 0 forever) ----
    for (int i = tid; i < 4 * 512; i += NTHREADS) ((unsigned char*)qpad)[i] = 0;

    // ---- build packed mask bits ----
    if (tid < 33) {
        if (tid == 32) smaskp[32] = 0u;
        else {
            unsigned int m = 0;
            #pragma unroll 4
            for (int j = 0; j < 32; ++j) m |= (mask_b[tid * 32 + j] ? 1u : 0u) << j;
            smaskp[tid] = m;
        }
    }

    // ---- raw emission registers per chain; step local L uses row ROW_OF(first+L-1)
    float em0[4][8], em1[4][8];
    #pragma unroll
    for (int c = 0; c < 4; ++c) {
        #pragma unroll
        for (int r = 0; r < 8; ++r) em0[c][r] = em_b[(size_t)ROW_OF(firstc[c] + r) * VV + nl];
        #pragma unroll
        for (int r = 0; r < 8; ++r) em1[c][r] = em_b[(size_t)ROW_OF(firstc[c] + 8 + r) * VV + nl];
    }
    float pep[4] = {0.f, 0.f, 0.f, 0.f};
    if (DIR) {
        #pragma unroll
        for (int c = 0; c < 4; ++c)
            pep[c] = __expf(em_b[(size_t)ROW_OF(firstc[c] - 1) * VV + nl]);
    }

    // ---- init states ----
    __syncthreads();   // zero-fill + smaskp visible
    if (tid < VV) {
        float a0 = DIR ? (end_trans[tid] + em_b[(size_t)(TT - 1) * VV + tid])
                       : (start_trans[tid] + em_b[tid]);
        qpad[0][0][tid] = f32_to_bf8(fminf(__expf(a0), 28672.f));
        unsigned char one = f32_to_bf8(1.0f);
        qpad[1][0][tid] = one;   // uniform warm init (scale irrelevant)
        qpad[2][0][tid] = one;
        qpad[3][0][tid] = one;
    }
    float carry[4] = {0.f,0.f,0.f,0.f}, Rv[4] = {0.f,0.f,0.f,0.f};
    float Pv[4] = {0.f,0.f,0.f,0.f}, csv[4] = {0.f,0.f,0.f,0.f};
    int cur = 0;
    __syncthreads();

    unsigned long long mk64[4];
    int shb[4];

#define GETMK(c, I) ((int)((mk64[c] >> (DIR ? (shb[c] + 15 - (I)) : (shb[c] + (I)))) & 1ull))

// one round = one step of each chain, fully branch-free.
// 12 DS reads (8 b128 + 4 u8), 24 MFMAs (kt-chained pairs), 4 epilogues,
// 4 DS writes, hook-captures from nb, one barrier. SGB pins reads+MFMAs.
#define ROUND(I)                                                               \
    {                                                                          \
        intx8 a0_[4], a1_[4];                                                  \
        unsigned char prevb_[4];                                               \
        _Pragma("unroll")                                                      \
        for (int c = 0; c < 4; ++c) {                                          \
            const intx8* qv = (const intx8*)qpad[c][cur];                      \
            a0_[c] = qv[quad];                                                 \
            a1_[c] = qv[quad + 4];                                             \
            prevb_[c] = qpad[c][cur][nl];                                      \
        }                                                                      \
        floatx4 acc_[4][3];                                                    \
        _Pragma("unroll")                                                      \
        for (int c = 0; c < 4; ++c) {                                          \
            _Pragma("unroll")                                                  \
            for (int h = 0; h < 3; ++h) {                                      \
                floatx4 z = (floatx4){0.f, 0.f, 0.f, 0.f};                     \
                floatx4 t0 = __builtin_amdgcn_mfma_scale_f32_16x16x128_f8f6f4( \
                    a0_[c], ef[h], z, 1, 0, 0, 0x7f7f7f7f, 0, 0x7f7f7f7f);     \
                acc_[c][h] = __builtin_amdgcn_mfma_scale_f32_16x16x128_f8f6f4( \
                    a1_[c], ef[3 + h], t0, 1, 0, 0, 0x7f7f7f7f, 0, 0x7f7f7f7f);\
            }                                                                  \
        }                                                                      \
        _Pragma("unroll")                                                      \
        for (int c = 0; c < 4; ++c) {                                          \
            int mk = GETMK(c, I);                                              \
            int q0i = __builtin_amdgcn_readfirstlane(a0_[c][0]);               \
            float q0 = bf8_to_f32((unsigned char)(q0i & 0xff));                \
            float rr = __builtin_amdgcn_rcpf(q0);                              \
            carry[c] += mk ? __log2f(q0) : 0.f;                                \
            float emraw = ((I) < 8) ? em0[c][(I) & 7] : em1[c][(I) & 7];       \
            float pe = __expf(emraw);                                          \
            float sc = pe * rr;                                                \
            float s0 = acc_[c][0][0];                                          \
            float s1 = acc_[c][1][0];                                          \
            float s2 = acc_[c][2][0];                                          \
            float vv = (quad == 1) ? s1 : ((quad == 2) ? s2 : s0);             \
            unsigned char nbm = f32_to_bf8(fminf(vv * sc, 28672.f));           \
            unsigned char nba;                                                 \
            if (DIR) nba = f32_to_bf8(fminf(bf8_to_f32(prevb_[c]) * pe *       \
                                 __builtin_amdgcn_rcpf(pep[c]), 28672.f));     \
            else nba = prevb_[c];                                              \
            unsigned char nb = mk ? nbm : nba;                                 \
            qpad[c][cur ^ 1][nl] = nb;                                         \
            if (DIR) pep[c] = pe;                                              \
            /* branch-free hook capture from nb (lane 0 holds state byte 0) */ \
            float q0n = bf8_to_f32(nb);                                        \
            float lg = __log2f(__int_as_float(                                 \
                __builtin_amdgcn_readfirstlane(__float_as_int(q0n))));         \
            int L = lb + (I) + 1;                                              \
            bool hitR = (L == capRc[c]);                                       \
            bool hitP = (L == capPc[c]);                                       \
            Rv[c]    = hitR ? lg : Rv[c];                                      \
            csv[c]   = hitP ? carry[c] : csv[c];                               \
            Pv[c]    = hitP ? lg : Pv[c];                                      \
            carry[c] = hitR ? 0.f : carry[c];                                  \
        }                                                                      \
        __builtin_amdgcn_sched_group_barrier(0x100, 12, 0);  /* DS reads */    \
        __builtin_amdgcn_sched_group_barrier(0x008, 24, 0);  /* MFMAs   */     \
        LBAR();                                                                \
        cur ^= 1;                                                              \
    }

    // ---- main loop: 9 windows x 16 rounds = 144 locksteps ----
    for (int w = 0; w < 9; ++w) {
        const int lb = 16 * w;
        #pragma unroll
        for (int c = 0; c < 4; ++c) {
            int gw = firstc[c] + lb;
            int base = DIR ? (1024 - gw - 15) : gw;
            unsigned lo = (unsigned)__builtin_amdgcn_readfirstlane((int)smaskp[base >> 5]);
            unsigned hi = (unsigned)__builtin_amdgcn_readfirstlane((int)smaskp[(base >> 5) + 1]);
            mk64[c] = (((unsigned long long)hi) << 32) | (unsigned long long)lo;
            shb[c] = base & 31;
        }
        ROUND(0) ROUND(1) ROUND(2) ROUND(3)
        ROUND(4) ROUND(5) ROUND(6) ROUND(7)
        {   // refill em0 (junk on last window; all addresses in-bounds)
            #pragma unroll
            for (int c = 0; c < 4; ++c) {
                #pragma unroll
                for (int r = 0; r < 8; ++r)
                    em0[c][r] = em_b[(size_t)ROW_OF(firstc[c] + lb + 16 + r) * VV + nl];
            }
        }
        ROUND(8) ROUND(9) ROUND(10) ROUND(11)
        ROUND(12) ROUND(13) ROUND(14) ROUND(15)
        {   // refill em1
            #pragma unroll
            for (int c = 0; c < 4; ++c) {
                #pragma unroll
                for (int r = 0; r < 8; ++r)
                    em1[c][r] = em_b[(size_t)ROW_OF(firstc[c] + lb + 24 + r) * VV + nl];
            }
        }
    }
#undef ROUND
#undef GETMK

    csv[3] = carry[3];   // c3 exports carry at end (no P)

    // ---- exports ----
    if (DIR == 0) {
        // F = state after t=512 (alpha_512 normalized)
        if (tid < VV) wsb[tid] = bf8_to_f32(qpad[3][cur][tid]);
    } else {
        // final plain matvec (no pe, no renorm): Bv from D_513, mask m_513
        const intx8* qv = (const intx8*)qpad[3][cur];
        intx8 A0 = qv[quad];
        intx8 A1 = qv[quad + 4];
        int mkf = (int)((smaskp[513 >> 5] >> (513 & 31)) & 1u);
        floatx4 aA[3], aB[3];
        #pragma unroll
        for (int h = 0; h < 3; ++h) {
            floatx4 z = (floatx4){0.f, 0.f, 0.f, 0.f};
            aA[h] = __builtin_amdgcn_mfma_scale_f32_16x16x128_f8f6f4(
                        A0, ef[h], z, 1, 0, 0, 0x7f7f7f7f, 0, 0x7f7f7f7f);
            aB[h] = __builtin_amdgcn_mfma_scale_f32_16x16x128_f8f6f4(
                        A1, ef[3 + h], z, 1, 0, 0, 0x7f7f7f7f, 0, 0x7f7f7f7f);
        }
        if (quad < 3) {
            float s0 = aA[0][0] + aB[0][0];
            float s1 = aA[1][0] + aB[1][0];
            float s2 = aA[2][0] + aB[2][0];
            float vv = (quad == 1) ? s1 : ((quad == 2) ? s2 : s0);
            if (!mkf) vv = bf8_to_f32(qpad[3][cur][nl]) * __builtin_amdgcn_rcpf(pep[3]);
            wsb[192 + nl] = vv;
        }
    }
    if (tid == 0) {
        #pragma unroll
        for (int c = 0; c < 4; ++c) {
            float contrib = csv[c] + ((c < 3) ? Pv[c] : 0.f) - ((c > 0) ? Rv[c] : 0.f);
            wsb[384 + DIR * 8 + c] = contrib;
        }
    }

    // ---- gold score + seq_len partials (this dir's t-range) ----
    float gp = 0.f, sl = 0.f;
    for (int t = tid; t < TT; t += NTHREADS) {
        int mk = (int)((smaskp[t >> 5] >> (t & 31)) & 1u);
        bool inS = DIR ? (t >= 512) : (t < 512);
        if (inS) sl += (float)mk;
        bool inG = DIR ? (t >= 513) : (t >= 1 && t <= 512);
        if (inG) {
            int tg  = tags[b * TT + t];
            int tgp = tags[b * TT + t - 1];
            float term = em_b[(size_t)t * VV + tg] + trans[tgp * VV + tg];
            gp += mk ? term : 0.f;
        }
    }
    #pragma unroll
    for (int off = 1; off < 64; off <<= 1) {
        gp += __shfl_xor(gp, off);
        sl += __shfl_xor(sl, off);
    }
    if (lane == 0) { wgs[wid] = gp; wsls[wid] = sl; }
    __syncthreads();
    if (tid == 0) {
        float g = 0.f, s = 0.f;
        for (int w = 0; w < 4; ++w) { g += wgs[w]; s += wsls[w]; }
        if (DIR == 0) {
            int tg0 = tags[b * TT];
            g += start_trans[tg0] + em_b[tg0];
        }
        wsb[384 + DIR * 8 + 4] = g;
        wsb[384 + DIR * 8 + 5] = s;
    }
    #undef ROW_OF
}

__launch_bounds__(NTHREADS, 1)
__attribute__((amdgpu_waves_per_eu(1, 1)))
__global__ void crf_ilp_kernel(const float* __restrict__ emissions,
                               const int* __restrict__ tags,
                               const int* __restrict__ mask,
                               const float* __restrict__ trans,
                               const float* __restrict__ start_trans,
                               const float* __restrict__ end_trans,
                               float* __restrict__ ws)
{
    if (blockIdx.y == 0)
        crf_body<0>(emissions, tags, mask, trans, start_trans, end_trans, ws);
    else
        crf_body<1>(emissions, tags, mask, trans, start_trans, end_trans, ws);
}

// combine: T = sum contribs; logden = LN2*T + log(dot(F,Bv));
// loss = (logden - gold)/seq_len
__global__ void crf_combine(const float* __restrict__ ws,
                            const int* __restrict__ tags,
                            const float* __restrict__ end_trans,
                            float* __restrict__ out)
{
    const int b = blockIdx.x;
    const int lane = threadIdx.x;   // 64 threads
    const float* wsb = ws + (size_t)b * WS_STRIDE;
    float s = 0.f;
    #pragma unroll
    for (int i = lane; i < VV; i += 64) s += wsb[i] * wsb[192 + i];
    #pragma unroll
    for (int off = 1; off < 64; off <<= 1) s += __shfl_xor(s, off);
    if (lane == 0) {
        float T = 0.f, gold = 0.f, seq = 0.f;
        for (int d = 0; d < 2; ++d) {
            const float* slot = wsb + 384 + d * 8;
            T    += slot[0] + slot[1] + slot[2] + slot[3];
            gold += slot[4];
            seq  += slot[5];
        }
        float logden = LN2 * T + __logf(s + 1e-8f);
        int seqs = (int)(seq + 0.5f);
        int last_idx = seqs - 1; if (last_idx < 0) last_idx = 0;
        gold += end_trans[tags[b * TT + last_idx]];
        float seqf = fmaxf((float)seqs, 1.0f);
        out[b] = (logden - gold) / seqf;
    }
}

extern "C" void kernel_launch(void* const* d_in, const int* in_sizes, int n_in,
                              void* d_out, int out_size, void* d_ws, size_t ws_size,
                              hipStream_t stream) {
    const float* emissions   = (const float*)d_in[0];
    const int*   tags        = (const int*)d_in[1];
    const int*   mask        = (const int*)d_in[2];
    const float* trans       = (const float*)d_in[3];
    const float* start_trans = (const float*)d_in[4];
    const float* end_trans   = (const float*)d_in[5];
    float* out = (float*)d_out;
    float* ws  = (float*)d_ws;   // 128*448*4 = 229376 B (proven budget)

    crf_ilp_kernel<<<dim3(BB, 2), NTHREADS, 0, stream>>>(
        emissions, tags, mask, trans, start_trans, end_trans, ws);
    crf_combine<<<BB, 64, 0, stream>>>(ws, tags, end_trans, out);
}

// Round 10
// 248.980 us; speedup vs baseline: 1.7420x; 1.0140x over previous
//
#include <hip/hip_runtime.h>

#define BB 128
#define TT 1024
#define VV 192
#define NTHREADS 256
#define LN2 0.69314718055994530942f
// per-batch ws: F[192], Bv[192], per-dir 8 slots: contrib[4], gold, seq
#define WS_STRIDE 448

typedef int   intx8   __attribute__((ext_vector_type(8)));
typedef float floatx2 __attribute__((ext_vector_type(2)));
typedef float floatx4 __attribute__((ext_vector_type(4)));

__device__ __forceinline__ float bf8_to_f32(unsigned char h) {
    floatx2 v = __builtin_amdgcn_cvt_pk_f32_bf8((int)(unsigned int)h, false);
    return v.x;
}
__device__ __forceinline__ unsigned char f32_to_bf8(float f) {
    int pk = __builtin_amdgcn_cvt_pk_bf8_f32(f, f, 0, false);
    return (unsigned char)(pk & 0xff);
}
__device__ __forceinline__ unsigned char f32_to_fp8(float f) {
    int pk = __builtin_amdgcn_cvt_pk_fp8_f32(f, f, 0, false);
    return (unsigned char)(pk & 0xff);
}

// LDS-only barrier: does NOT drain vmcnt (global loads stay in flight)
#define LBAR() __asm__ volatile("s_waitcnt lgkmcnt(0)\n\ts_barrier" ::: "memory")

// A fmt = bf8 (state), B fmt = fp8 (ef), scales = 1.0
#define MFMA_SC(A, B, C) __builtin_amdgcn_mfma_scale_f32_16x16x128_f8f6f4( \
    (A), (B), (C), 1, 0, 0, 0x7f7f7f7f, 0, 0x7f7f7f7f)

// Dual-path 4-chain kernel. Probe verifies the packed A-row mapping at
// runtime (chains initialized to 1,2,4 — scale-invariant recursion, any
// positive const works). Probe OK -> packed path (6 MFMA/round); else ->
// R8's proven broadcast path (24 MFMA/round).
// Chain geometry per dir (R5/R7/R8-validated warm-up chunking):
//  c0: first=1,  no warm, P at L=128
//  c1: first=113, R at L=16, P at L=144 (=step 256)
//  c2: first=241, R at L=16, P at L=144 (=step 384)
//  c3 fwd: first=369, R at L=16, real to L=144 (=t=512), exports F
//  c3 bwd: first=367, R at L=18, real to L=144 (=u=510), final matvec -> Bv
// contrib_c = carry_c + (c<3 ? P_c : 0) - (c>0 ? R_c : 0); T = sum contribs.
template<int DIR>
__device__ __forceinline__ void crf_body(const float* __restrict__ emissions,
                                         const int* __restrict__ tags,
                                         const int* __restrict__ mask,
                                         const float* __restrict__ trans,
                                         const float* __restrict__ start_trans,
                                         const float* __restrict__ end_trans,
                                         float* __restrict__ ws)
{
    const int b = blockIdx.x;
    const int tid = threadIdx.x;
    const int lane = tid & 63;
    const int wid = tid >> 6;        // 0..3
    const int quad = lane >> 4;      // 0..3
    const int col = lane & 15;       // 0..15

    __shared__ __align__(16) unsigned char qpad[4][2][256];
    __shared__ unsigned int smaskp[33];   // packed mask bits, word 32 = 0 pad
    __shared__ float wgs[4], wsls[4];
    __shared__ int okflag;

    const float* em_b = emissions + (size_t)b * TT * VV;
    const int* mask_b = mask + b * TT;
    float* wsb = ws + (size_t)b * WS_STRIDE;

    const int col0 = wid * 48 + col;                        // packed-path cols
    const int nlT  = wid * 48 + (quad < 3 ? quad : 0) * 16 + col;  // broadcast col

    const int firstc[4] = {1, 113, 241, DIR ? 367 : 369};
    const int capRc[4]  = {0, 16, 16, DIR ? 18 : 16};
    const int capPc[4]  = {128, 144, 144, 0};

    #define ROW_OF(x) (DIR ? (TT - 1 - (x)) : (x))

    // ---- E fragments, e4m3, MX 16x16x128 B-operand (shared by all chains) ----
    intx8 ef[6];
    #pragma unroll
    for (int kt = 0; kt < 2; ++kt) {
        #pragma unroll
        for (int h = 0; h < 3; ++h) {
            const int n = wid * 48 + h * 16 + col;
            intx8 v;
            #pragma unroll
            for (int w = 0; w < 8; ++w) {
                unsigned int word = 0;
                #pragma unroll
                for (int by = 0; by < 4; ++by) {
                    int k = kt * 128 + quad * 32 + w * 4 + by;
                    float x = (k < VV) ? __expf(trans[DIR ? (k + n * VV) : (k * VV + n)]) : 0.f;
                    word |= (unsigned int)f32_to_fp8(x) << (8 * by);
                }
                v[w] = (int)word;
            }
            ef[kt * 3 + h] = v;
        }
    }

    // ---- zero all Q buffers (pad bytes 192..255 must stay 0 forever) ----
    for (int i = tid; i < 4 * 512; i += NTHREADS) ((unsigned char*)qpad)[i] = 0;

    // ---- build packed mask bits ----
    if (tid < 33) {
        if (tid == 32) smaskp[32] = 0u;
        else {
            unsigned int m = 0;
            #pragma unroll 4
            for (int j = 0; j < 32; ++j) m |= (mask_b[tid * 32 + j] ? 1u : 0u) << j;
            smaskp[tid] = m;
        }
    }
    if (tid == 0) okflag = 1;

    // ---- init states: chain 0 real; 1,2,3 = consts 1,2,4 (scale-invariant) ----
    __syncthreads();   // zero-fill + smaskp + okflag visible
    if (tid < VV) {
        float a0 = DIR ? (end_trans[tid] + em_b[(size_t)(TT - 1) * VV + tid])
                       : (start_trans[tid] + em_b[tid]);
        qpad[0][0][tid] = f32_to_bf8(fminf(__expf(a0), 28672.f));
        qpad[1][0][tid] = f32_to_bf8(1.0f);
        qpad[2][0][tid] = f32_to_bf8(2.0f);
        qpad[3][0][tid] = f32_to_bf8(4.0f);
    }
    __syncthreads();

    // ---- PROBE: does packed-A decode work on this hardware? ----
    {
        int okl = 1;
        const intx8* qv0 = (const intx8*)qpad[0][0];
        intx8 b0 = qv0[quad], b1 = qv0[quad + 4];
        const intx8* qvp = (const intx8*)qpad[lane & 3][0];
        intx8 p0 = qvp[quad], p1 = qvp[quad + 4];
        floatx4 z = (floatx4){0.f, 0.f, 0.f, 0.f};
        floatx4 tb = MFMA_SC(b0, ef[0], z);
        floatx4 ab = MFMA_SC(b1, ef[3], tb);
        floatx4 tp = MFMA_SC(p0, ef[0], z);
        floatx4 ap = MFMA_SC(p1, ef[3], tp);
        // reg0 must equal broadcast chain-0 (bit-identical inputs)
        okl &= (fabsf(ap[0] - ab[0]) <= 1e-3f * (fabsf(ab[0]) + 1.f)) ? 1 : 0;
        // reg1/2/3 must be chains 1/2/3 (consts 1,2,4 -> unique ratios)
        okl &= (fabsf(ap[2] - 2.f * ap[1]) <= 1e-3f * (fabsf(ap[2]) + 1.f)) ? 1 : 0;
        okl &= (fabsf(ap[3] - 4.f * ap[1]) <= 1e-3f * (fabsf(ap[3]) + 1.f)) ? 1 : 0;
        unsigned long long vt = __ballot(okl);
        if (lane == 0 && vt != 0xFFFFFFFFFFFFFFFFull) okflag = 0;
    }
    __syncthreads();
    const bool usePacked = (okflag != 0);

    float carry[4] = {0.f,0.f,0.f,0.f}, Rv[4] = {0.f,0.f,0.f,0.f};
    float Pv[4] = {0.f,0.f,0.f,0.f}, csv[4] = {0.f,0.f,0.f,0.f};
    int cur = 0;
    unsigned long long mk64[4];
    int shb[4];

#define FETCHWIN(lb_)                                                          \
    {                                                                          \
        _Pragma("unroll")                                                      \
        for (int c = 0; c < 4; ++c) {                                          \
            int gw = firstc[c] + (lb_);                                        \
            int base = DIR ? (1024 - gw - 15) : gw;                            \
            unsigned lo = (unsigned)__builtin_amdgcn_readfirstlane((int)smaskp[base >> 5]);      \
            unsigned hi = (unsigned)__builtin_amdgcn_readfirstlane((int)smaskp[(base >> 5) + 1]);\
            mk64[c] = (((unsigned long long)hi) << 32) | (unsigned long long)lo;\
            shb[c] = base & 31;                                                \
        }                                                                      \
    }
#define GETMK(c, I) ((int)((mk64[c] >> (DIR ? (shb[c] + 15 - (I)) : (shb[c] + (I)))) & 1ull))

    if (usePacked) {
        // ================= PACKED PATH: 6 MFMAs/round =================
        const int flc = (quad == 1) ? firstc[1] : (quad == 2) ? firstc[2]
                      : (quad == 3) ? firstc[3] : firstc[0];
        float em0[3][8], em1[3][8];
        #pragma unroll
        for (int h = 0; h < 3; ++h) {
            #pragma unroll
            for (int r = 0; r < 8; ++r) {
                em0[h][r] = em_b[(size_t)ROW_OF(flc + r) * VV + col0 + h * 16];
                em1[h][r] = em_b[(size_t)ROW_OF(flc + 8 + r) * VV + col0 + h * 16];
            }
        }
        float pep[3] = {0.f, 0.f, 0.f};
        if (DIR) {
            #pragma unroll
            for (int h = 0; h < 3; ++h)
                pep[h] = __expf(em_b[(size_t)ROW_OF(flc - 1) * VV + col0 + h * 16]);
        }

// step L = lb+I+1. Hooks at round top use q0c (= state after step L-1);
// q0 per chain read DIRECTLY from LDS byte0 (no lane-map assumption).
#define PROUND(I)                                                              \
    {                                                                          \
        const intx8* qv_ = (const intx8*)qpad[lane & 3][cur];                  \
        intx8 a0_ = qv_[quad];                                                 \
        intx8 a1_ = qv_[quad + 4];                                             \
        float q0c[4];                                                          \
        q0c[0] = bf8_to_f32(qpad[0][cur][0]);                                  \
        q0c[1] = bf8_to_f32(qpad[1][cur][0]);                                  \
        q0c[2] = bf8_to_f32(qpad[2][cur][0]);                                  \
        q0c[3] = bf8_to_f32(qpad[3][cur][0]);                                  \
        unsigned char pb0 = qpad[quad][cur][col0];                             \
        unsigned char pb1 = qpad[quad][cur][col0 + 16];                        \
        unsigned char pb2 = qpad[quad][cur][col0 + 32];                        \
        /* hooks for step L-1 */                                               \
        {                                                                      \
            int Lm1 = lb + (I);                                                \
            _Pragma("unroll")                                                  \
            for (int c = 0; c < 4; ++c) {                                      \
                float lgc = __log2f(q0c[c]);                                   \
                bool hitR = (Lm1 == capRc[c]);                                 \
                bool hitP = (Lm1 == capPc[c]);                                 \
                Rv[c]    = hitR ? lgc : Rv[c];                                 \
                csv[c]   = hitP ? carry[c] : csv[c];                           \
                Pv[c]    = hitP ? lgc : Pv[c];                                 \
                carry[c] = hitR ? 0.f : carry[c];                              \
            }                                                                  \
        }                                                                      \
        floatx4 acc_[3];                                                       \
        _Pragma("unroll")                                                      \
        for (int h = 0; h < 3; ++h) {                                          \
            floatx4 z_ = (floatx4){0.f, 0.f, 0.f, 0.f};                        \
            floatx4 t0_ = MFMA_SC(a0_, ef[h], z_);                             \
            acc_[h] = MFMA_SC(a1_, ef[3 + h], t0_);                            \
        }                                                                      \
        _Pragma("unroll")                                                      \
        for (int c = 0; c < 4; ++c)                                            \
            carry[c] += GETMK(c, I) ? __log2f(q0c[c]) : 0.f;                   \
        float q0q = (quad == 1) ? q0c[1] : (quad == 2) ? q0c[2]                \
                  : (quad == 3) ? q0c[3] : q0c[0];                             \
        float rrq = __builtin_amdgcn_rcpf(q0q);                                \
        int mkq   = (quad == 1) ? GETMK(1, I) : (quad == 2) ? GETMK(2, I)      \
                  : (quad == 3) ? GETMK(3, I) : GETMK(0, I);                   \
        _Pragma("unroll")                                                      \
        for (int h = 0; h < 3; ++h) {                                          \
            float emr = ((I) < 8) ? em0[h][(I) & 7] : em1[h][(I) & 7];         \
            float pe = __expf(emr);                                            \
            float vv = (quad == 1) ? acc_[h][1] : (quad == 2) ? acc_[h][2]     \
                     : (quad == 3) ? acc_[h][3] : acc_[h][0];                  \
            unsigned char pb = (h == 0) ? pb0 : (h == 1) ? pb1 : pb2;          \
            unsigned char nbm = f32_to_bf8(fminf(vv * pe * rrq, 28672.f));     \
            unsigned char nba;                                                 \
            if (DIR) nba = f32_to_bf8(fminf(bf8_to_f32(pb) * pe *              \
                                 __builtin_amdgcn_rcpf(pep[h]), 28672.f));     \
            else nba = pb;                                                     \
            qpad[quad][cur ^ 1][col0 + h * 16] = mkq ? nbm : nba;              \
            if (DIR) pep[h] = pe;                                              \
        }                                                                      \
        __builtin_amdgcn_sched_group_barrier(0x100, 11, 0);                    \
        __builtin_amdgcn_sched_group_barrier(0x008, 6, 0);                     \
        LBAR();                                                                \
        cur ^= 1;                                                              \
    }

        for (int w = 0; w < 9; ++w) {
            const int lb = 16 * w;
            FETCHWIN(lb)
            PROUND(0) PROUND(1) PROUND(2) PROUND(3)
            PROUND(4) PROUND(5) PROUND(6) PROUND(7)
            {
                #pragma unroll
                for (int h = 0; h < 3; ++h)
                    #pragma unroll
                    for (int r = 0; r < 8; ++r)
                        em0[h][r] = em_b[(size_t)ROW_OF(flc + lb + 16 + r) * VV + col0 + h * 16];
            }
            PROUND(8) PROUND(9) PROUND(10) PROUND(11)
            PROUND(12) PROUND(13) PROUND(14) PROUND(15)
            {
                #pragma unroll
                for (int h = 0; h < 3; ++h)
                    #pragma unroll
                    for (int r = 0; r < 8; ++r)
                        em1[h][r] = em_b[(size_t)ROW_OF(flc + lb + 24 + r) * VV + col0 + h * 16];
            }
        }
#undef PROUND
        // post-loop captures (capP==144 for c1,c2; c3 carry)
        Pv[1] = __log2f(bf8_to_f32(qpad[1][cur][0]));  csv[1] = carry[1];
        Pv[2] = __log2f(bf8_to_f32(qpad[2][cur][0]));  csv[2] = carry[2];
        csv[3] = carry[3];
    } else {
        // ================= BROADCAST PATH: R8 verbatim =================
        float em0b[4][8], em1b[4][8];
        #pragma unroll
        for (int c = 0; c < 4; ++c) {
            #pragma unroll
            for (int r = 0; r < 8; ++r) {
                em0b[c][r] = em_b[(size_t)ROW_OF(firstc[c] + r) * VV + nlT];
                em1b[c][r] = em_b[(size_t)ROW_OF(firstc[c] + 8 + r) * VV + nlT];
            }
        }
        float pepb[4] = {0.f, 0.f, 0.f, 0.f};
        if (DIR) {
            #pragma unroll
            for (int c = 0; c < 4; ++c)
                pepb[c] = __expf(em_b[(size_t)ROW_OF(firstc[c] - 1) * VV + nlT]);
        }

#define BROUND(I)                                                              \
    {                                                                          \
        intx8 a0_[4], a1_[4];                                                  \
        unsigned char prevb_[4];                                               \
        _Pragma("unroll")                                                      \
        for (int c = 0; c < 4; ++c) {                                          \
            const intx8* qv = (const intx8*)qpad[c][cur];                      \
            a0_[c] = qv[quad];                                                 \
            a1_[c] = qv[quad + 4];                                             \
            prevb_[c] = qpad[c][cur][nlT];                                     \
        }                                                                      \
        floatx4 acc_[4][3];                                                    \
        _Pragma("unroll")                                                      \
        for (int c = 0; c < 4; ++c) {                                          \
            _Pragma("unroll")                                                  \
            for (int h = 0; h < 3; ++h) {                                      \
                floatx4 z = (floatx4){0.f, 0.f, 0.f, 0.f};                     \
                floatx4 t0 = MFMA_SC(a0_[c], ef[h], z);                        \
                acc_[c][h] = MFMA_SC(a1_[c], ef[3 + h], t0);                   \
            }                                                                  \
        }                                                                      \
        _Pragma("unroll")                                                      \
        for (int c = 0; c < 4; ++c) {                                          \
            int mk = GETMK(c, I);                                              \
            int q0i = __builtin_amdgcn_readfirstlane(a0_[c][0]);               \
            float q0 = bf8_to_f32((unsigned char)(q0i & 0xff));                \
            float rr = __builtin_amdgcn_rcpf(q0);                              \
            carry[c] += mk ? __log2f(q0) : 0.f;                                \
            float emraw = ((I) < 8) ? em0b[c][(I) & 7] : em1b[c][(I) & 7];     \
            float pe = __expf(emraw);                                          \
            float sc = pe * rr;                                                \
            float s0 = acc_[c][0][0];                                          \
            float s1 = acc_[c][1][0];                                          \
            float s2 = acc_[c][2][0];                                          \
            float vv = (quad == 1) ? s1 : ((quad == 2) ? s2 : s0);             \
            unsigned char nbm = f32_to_bf8(fminf(vv * sc, 28672.f));           \
            unsigned char nba;                                                 \
            if (DIR) nba = f32_to_bf8(fminf(bf8_to_f32(prevb_[c]) * pe *       \
                                 __builtin_amdgcn_rcpf(pepb[c]), 28672.f));    \
            else nba = prevb_[c];                                              \
            unsigned char nb = mk ? nbm : nba;                                 \
            qpad[c][cur ^ 1][nlT] = nb;                                        \
            if (DIR) pepb[c] = pe;                                             \
            float q0n = bf8_to_f32(nb);                                        \
            float lg = __log2f(__int_as_float(                                 \
                __builtin_amdgcn_readfirstlane(__float_as_int(q0n))));         \
            int L = lb + (I) + 1;                                              \
            bool hitR = (L == capRc[c]);                                       \
            bool hitP = (L == capPc[c]);                                       \
            Rv[c]    = hitR ? lg : Rv[c];                                      \
            csv[c]   = hitP ? carry[c] : csv[c];                               \
            Pv[c]    = hitP ? lg : Pv[c];                                      \
            carry[c] = hitR ? 0.f : carry[c];                                  \
        }                                                                      \
        __builtin_amdgcn_sched_group_barrier(0x100, 12, 0);                    \
        __builtin_amdgcn_sched_group_barrier(0x008, 24, 0);                    \
        LBAR();                                                                \
        cur ^= 1;                                                              \
    }

        for (int w = 0; w < 9; ++w) {
            const int lb = 16 * w;
            FETCHWIN(lb)
            BROUND(0) BROUND(1) BROUND(2) BROUND(3)
            BROUND(4) BROUND(5) BROUND(6) BROUND(7)
            {
                #pragma unroll
                for (int c = 0; c < 4; ++c)
                    #pragma unroll
                    for (int r = 0; r < 8; ++r)
                        em0b[c][r] = em_b[(size_t)ROW_OF(firstc[c] + lb + 16 + r) * VV + nlT];
            }
            BROUND(8) BROUND(9) BROUND(10) BROUND(11)
            BROUND(12) BROUND(13) BROUND(14) BROUND(15)
            {
                #pragma unroll
                for (int c = 0; c < 4; ++c)
                    #pragma unroll
                    for (int r = 0; r < 8; ++r)
                        em1b[c][r] = em_b[(size_t)ROW_OF(firstc[c] + lb + 24 + r) * VV + nlT];
            }
        }
#undef BROUND
        csv[3] = carry[3];
    }
#undef FETCHWIN
#undef GETMK

    // ---- exports (shared; cur == 0 after 144 flips in either path) ----
    if (DIR == 0) {
        if (tid < VV) wsb[tid] = bf8_to_f32(qpad[3][cur][tid]);
    } else {
        // final plain matvec (broadcast A): Bv from D_513, mask m_513
        const intx8* qv = (const intx8*)qpad[3][cur];
        intx8 A0 = qv[quad];
        intx8 A1 = qv[quad + 4];
        int mkf = (int)((smaskp[513 >> 5] >> (513 & 31)) & 1u);
        floatx4 aA[3];
        #pragma unroll
        for (int h = 0; h < 3; ++h) {
            floatx4 z = (floatx4){0.f, 0.f, 0.f, 0.f};
            floatx4 t0 = MFMA_SC(A0, ef[h], z);
            aA[h] = MFMA_SC(A1, ef[3 + h], t0);
        }
        if (quad < 3) {
            float vv = (quad == 1) ? aA[1][0] : (quad == 2) ? aA[2][0] : aA[0][0];
            if (!mkf) {
                float peT = __expf(em_b[(size_t)513 * VV + nlT]);
                vv = bf8_to_f32(qpad[3][cur][nlT]) * __builtin_amdgcn_rcpf(peT);
            }
            wsb[192 + nlT] = vv;
        }
    }
    if (tid == 0) {
        #pragma unroll
        for (int c = 0; c < 4; ++c) {
            float contrib = csv[c] + ((c < 3) ? Pv[c] : 0.f) - ((c > 0) ? Rv[c] : 0.f);
            wsb[384 + DIR * 8 + c] = contrib;
        }
    }

    // ---- gold score + seq_len partials (this dir's t-range) ----
    float gp = 0.f, sl = 0.f;
    for (int t = tid; t < TT; t += NTHREADS) {
        int mk = (int)((smaskp[t >> 5] >> (t & 31)) & 1u);
        bool inS = DIR ? (t >= 512) : (t < 512);
        if (inS) sl += (float)mk;
        bool inG = DIR ? (t >= 513) : (t >= 1 && t <= 512);
        if (inG) {
            int tg  = tags[b * TT + t];
            int tgp = tags[b * TT + t - 1];
            float term = em_b[(size_t)t * VV + tg] + trans[tgp * VV + tg];
            gp += mk ? term : 0.f;
        }
    }
    #pragma unroll
    for (int off = 1; off < 64; off <<= 1) {
        gp += __shfl_xor(gp, off);
        sl += __shfl_xor(sl, off);
    }
    if (lane == 0) { wgs[wid] = gp; wsls[wid] = sl; }
    __syncthreads();
    if (tid == 0) {
        float g = 0.f, s = 0.f;
        for (int w = 0; w < 4; ++w) { g += wgs[w]; s += wsls[w]; }
        if (DIR == 0) {
            int tg0 = tags[b * TT];
            g += start_trans[tg0] + em_b[tg0];
        }
        wsb[384 + DIR * 8 + 4] = g;
        wsb[384 + DIR * 8 + 5] = s;
    }
    #undef ROW_OF
}

__launch_bounds__(NTHREADS, 1)
__attribute__((amdgpu_waves_per_eu(1, 1)))
__global__ void crf_dual_kernel(const float* __restrict__ emissions,
                                const int* __restrict__ tags,
                                const int* __restrict__ mask,
                                const float* __restrict__ trans,
                                const float* __restrict__ start_trans,
                                const float* __restrict__ end_trans,
                                float* __restrict__ ws)
{
    if (blockIdx.y == 0)
        crf_body<0>(emissions, tags, mask, trans, start_trans, end_trans, ws);
    else
        crf_body<1>(emissions, tags, mask, trans, start_trans, end_trans, ws);
}

// combine: T = sum contribs; logden = LN2*T + log(dot(F,Bv));
// loss = (logden - gold)/seq_len
__global__ void crf_combine(const float* __restrict__ ws,
                            const int* __restrict__ tags,
                            const float* __restrict__ end_trans,
                            float* __restrict__ out)
{
    const int b = blockIdx.x;
    const int lane = threadIdx.x;   // 64 threads
    const float* wsb = ws + (size_t)b * WS_STRIDE;
    float s = 0.f;
    #pragma unroll
    for (int i = lane; i < VV; i += 64) s += wsb[i] * wsb[192 + i];
    #pragma unroll
    for (int off = 1; off < 64; off <<= 1) s += __shfl_xor(s, off);
    if (lane == 0) {
        float T = 0.f, gold = 0.f, seq = 0.f;
        for (int d = 0; d < 2; ++d) {
            const float* slot = wsb + 384 + d * 8;
            T    += slot[0] + slot[1] + slot[2] + slot[3];
            gold += slot[4];
            seq  += slot[5];
        }
        float logden = LN2 * T + __logf(s + 1e-8f);
        int seqs = (int)(seq + 0.5f);
        int last_idx = seqs - 1; if (last_idx < 0) last_idx = 0;
        gold += end_trans[tags[b * TT + last_idx]];
        float seqf = fmaxf((float)seqs, 1.0f);
        out[b] = (logden - gold) / seqf;
    }
}

extern "C" void kernel_launch(void* const* d_in, const int* in_sizes, int n_in,
                              void* d_out, int out_size, void* d_ws, size_t ws_size,
                              hipStream_t stream) {
    const float* emissions   = (const float*)d_in[0];
    const int*   tags        = (const int*)d_in[1];
    const int*   mask        = (const int*)d_in[2];
    const float* trans       = (const float*)d_in[3];
    const float* start_trans = (const float*)d_in[4];
    const float* end_trans   = (const float*)d_in[5];
    float* out = (float*)d_out;
    float* ws  = (float*)d_ws;   // 128*448*4 = 229376 B (proven budget)

    crf_dual_kernel<<<dim3(BB, 2), NTHREADS, 0, stream>>>(
        emissions, tags, mask, trans, start_trans, end_trans, ws);
    crf_combine<<<BB, 64, 0, stream>>>(ws, tags, end_trans, out);
}